// Round 2
// baseline (512.755 us; speedup 1.0000x reference)
//
#include <hip/hip_runtime.h>
#include <hip/hip_cooperative_groups.h>
#include <cstdint>

namespace cg = cooperative_groups;

// ---------------------------------------------------------------------------
// NeuralODE (DoPri5 adaptive, 64-iter budget) on MI355X — Round 2.
// R=2 rows per WG (128 WGs x 256 thr): each weight load feeds BOTH rows ->
// L2 weight traffic halves (was the measured bottleneck: 34 TB/s aggregate).
// Weights packed to f16; inner products via v_dot2_f32_f16 (2 MAC/lane/instr,
// no unpack ALU). Row-local structure, 1 grid sync per iteration (err_norm).
// FSAL k0<-k6 on accept; early uniform break at t>=1.
// ---------------------------------------------------------------------------

#define WS_W1P_OFF 0
#define WS_W2P_OFF (512 * 1024)
#define WS_ERR_OFF (1024 * 1024)

typedef _Float16 half2v __attribute__((ext_vector_type(2)));
union H2U { uint32_t u; half2v h; };

__device__ __forceinline__ uint32_t packh2(float a, float b) {
  H2U r; r.h = half2v{(_Float16)a, (_Float16)b}; return r.u;
}
__device__ __forceinline__ float fdot2(uint32_t w, uint32_t x, float acc) {
  H2U uw, ux; uw.u = w; ux.u = x;
  return __builtin_amdgcn_fdot2(uw.h, ux.h, acc, false);
}

// f(x, t) for TWO batch rows. 256 threads; thread owns output col tid (both
// rows) and hidden cols [4t,4t+3] (both rows).
__device__ __forceinline__ float2 eval_vf2(
    float xi0, float xi1, float t_i, int tid,
    const uint4* __restrict__ W1p, const uint4* __restrict__ W2p,
    const float* __restrict__ w1t, const float* __restrict__ b1,
    const float* __restrict__ b2, _Float16* sxi, _Float16* sh) {
  sxi[tid] = (_Float16)xi0;
  sxi[256 + tid] = (_Float16)xi1;
  __syncthreads();

  // GEMM1: h[r][4t..4t+3] = tanh(xi_r . W1[:, c] + t*W1[256,c] + b1[c])
  const float4 bv = reinterpret_cast<const float4*>(const_cast<float*>(b1))[tid];
  const float4 wt = reinterpret_cast<const float4*>(const_cast<float*>(w1t))[tid];
  float a00 = fmaf(t_i, wt.x, bv.x), a01 = fmaf(t_i, wt.y, bv.y);
  float a02 = fmaf(t_i, wt.z, bv.z), a03 = fmaf(t_i, wt.w, bv.w);
  float a10 = a00, a11 = a01, a12 = a02, a13 = a03;
  const uint32_t* sx0 = reinterpret_cast<const uint32_t*>(sxi);
  const uint32_t* sx1 = reinterpret_cast<const uint32_t*>(sxi + 256);
#pragma unroll 4
  for (int c2 = 0; c2 < 128; ++c2) {
    uint4 w = W1p[(c2 << 8) + tid];  // K-pair (2c2,2c2+1) x cols 4t..4t+3, f16
    uint32_t x0 = sx0[c2];           // LDS broadcast (same addr all lanes)
    uint32_t x1 = sx1[c2];
    a00 = fdot2(w.x, x0, a00); a01 = fdot2(w.y, x0, a01);
    a02 = fdot2(w.z, x0, a02); a03 = fdot2(w.w, x0, a03);
    a10 = fdot2(w.x, x1, a10); a11 = fdot2(w.y, x1, a11);
    a12 = fdot2(w.z, x1, a12); a13 = fdot2(w.w, x1, a13);
  }
  uint2 p0 = make_uint2(packh2(tanhf(a00), tanhf(a01)),
                        packh2(tanhf(a02), tanhf(a03)));
  uint2 p1 = make_uint2(packh2(tanhf(a10), tanhf(a11)),
                        packh2(tanhf(a12), tanhf(a13)));
  reinterpret_cast<uint2*>(sh)[tid] = p0;         // row0: f16 idx 4t
  reinterpret_cast<uint2*>(sh)[256 + tid] = p1;   // row1
  __syncthreads();

  // GEMM2: k[r][t] = h_r . W2[:, t] + b2[t]
  float k0 = b2[tid], k1 = k0;
  const uint4* sh40 = reinterpret_cast<const uint4*>(sh);          // 8 f16/ld
  const uint4* sh41 = reinterpret_cast<const uint4*>(sh + 1024);
#pragma unroll 4
  for (int k4 = 0; k4 < 128; ++k4) {
    uint4 w = W2p[(k4 << 8) + tid];  // K-pairs (8k4..8k4+7) at col t, f16
    uint4 h0 = sh40[k4];             // LDS broadcast
    uint4 h1 = sh41[k4];
    k0 = fdot2(w.x, h0.x, k0); k0 = fdot2(w.y, h0.y, k0);
    k0 = fdot2(w.z, h0.z, k0); k0 = fdot2(w.w, h0.w, k0);
    k1 = fdot2(w.x, h1.x, k1); k1 = fdot2(w.y, h1.y, k1);
    k1 = fdot2(w.z, h1.z, k1); k1 = fdot2(w.w, h1.w, k1);
  }
  return make_float2(k0, k1);
}

extern "C" __global__ void __launch_bounds__(256) neural_ode_dopri5(
    const float* __restrict__ x0, const float* __restrict__ W1,
    const float* __restrict__ b1, const float* __restrict__ W2,
    const float* __restrict__ b2, float* __restrict__ out,
    uint4* __restrict__ W1p, uint4* __restrict__ W2p, float* errAcc) {
  cg::grid_group gridg = cg::this_grid();
  const int tid = threadIdx.x;
  const int g = (blockIdx.x << 8) + tid;  // 0..32767

  // ---- prologue: pack weights to f16; zero err slots ----------------------
  {
    const int c2 = g >> 8, j = g & 255;
    const float* r0 = W1 + (2 * c2) * 1024 + 4 * j;
    float4 a = *reinterpret_cast<const float4*>(r0);
    float4 b = *reinterpret_cast<const float4*>(r0 + 1024);
    W1p[g] = make_uint4(packh2(a.x, b.x), packh2(a.y, b.y),
                        packh2(a.z, b.z), packh2(a.w, b.w));
    const int k4 = g >> 8, c = g & 255;
    const float* base = W2 + (8 * k4) * 256 + c;
    W2p[g] = make_uint4(packh2(base[0], base[256]),
                        packh2(base[512], base[768]),
                        packh2(base[1024], base[1280]),
                        packh2(base[1536], base[1792]));
  }
  if (g < 64) errAcc[g] = 0.0f;
  gridg.sync();

  // ---- Butcher tableau ----------------------------------------------------
  const float a20 = (float)(3.0 / 40.0),      a21 = (float)(9.0 / 40.0);
  const float a30 = (float)(44.0 / 45.0),     a31 = (float)(-56.0 / 15.0);
  const float a32 = (float)(32.0 / 9.0);
  const float a40 = (float)(19372.0 / 6561.0), a41 = (float)(-25360.0 / 2187.0);
  const float a42 = (float)(64448.0 / 6561.0), a43 = (float)(-212.0 / 729.0);
  const float a50 = (float)(9017.0 / 3168.0),  a51 = (float)(-355.0 / 33.0);
  const float a52 = (float)(46732.0 / 5247.0), a53 = (float)(49.0 / 176.0);
  const float a54 = (float)(-5103.0 / 18656.0);
  const float b50 = (float)(35.0 / 384.0),     b52 = (float)(500.0 / 1113.0);
  const float b53 = (float)(125.0 / 192.0),    b54 = (float)(-2187.0 / 6784.0);
  const float b55 = (float)(11.0 / 84.0);
  const float c1 = (float)(1.0 / 5.0), c2c = (float)(3.0 / 10.0);
  const float c3 = (float)(4.0 / 5.0), c4c = (float)(8.0 / 9.0);
  const float d0 = (float)(35.0 / 384.0 - 5179.0 / 57600.0);
  const float d2 = (float)(500.0 / 1113.0 - 7571.0 / 16695.0);
  const float d3 = (float)(125.0 / 192.0 - 393.0 / 640.0);
  const float d4 = (float)(-2187.0 / 6784.0 + 92097.0 / 339200.0);
  const float d5 = (float)(11.0 / 84.0 - 187.0 / 2100.0);
  const float d6 = (float)(-1.0 / 40.0);

  __shared__ _Float16 sxi[2 * 256];
  __shared__ _Float16 sh[2 * 1024];
  __shared__ float sred[4];

  const float* w1t = W1 + 256 * 1024;
  const int row0 = 2 * blockIdx.x;
  const float x0v0 = x0[row0 * 256 + tid];
  const float x0v1 = x0[(row0 + 1) * 256 + tid];
  float xA = x0v0, xB = x0v1;
  float t = 0.0f, dt = 0.05f;

  float2 k0 = eval_vf2(xA, xB, 0.0f, tid, W1p, W2p, w1t, b1, b2, sxi, sh);
  float2 k1, k2, k3, k4, k5, k6;

  for (int it = 0; it < 64; ++it) {
    if (t >= 1.0f) break;  // uniform across grid (controller is global)
    float dt_c = fmaxf(fminf(dt, 1.0f - t), 0.0f);

    float xiA = fmaf(dt_c * 0.2f, k0.x, xA);
    float xiB = fmaf(dt_c * 0.2f, k0.y, xB);
    k1 = eval_vf2(xiA, xiB, fmaf(c1, dt_c, t), tid, W1p, W2p, w1t, b1, b2, sxi, sh);

    xiA = fmaf(dt_c * a21, k1.x, fmaf(dt_c * a20, k0.x, xA));
    xiB = fmaf(dt_c * a21, k1.y, fmaf(dt_c * a20, k0.y, xB));
    k2 = eval_vf2(xiA, xiB, fmaf(c2c, dt_c, t), tid, W1p, W2p, w1t, b1, b2, sxi, sh);

    xiA = fmaf(dt_c * a32, k2.x, fmaf(dt_c * a31, k1.x, fmaf(dt_c * a30, k0.x, xA)));
    xiB = fmaf(dt_c * a32, k2.y, fmaf(dt_c * a31, k1.y, fmaf(dt_c * a30, k0.y, xB)));
    k3 = eval_vf2(xiA, xiB, fmaf(c3, dt_c, t), tid, W1p, W2p, w1t, b1, b2, sxi, sh);

    xiA = fmaf(dt_c * a43, k3.x, fmaf(dt_c * a42, k2.x,
          fmaf(dt_c * a41, k1.x, fmaf(dt_c * a40, k0.x, xA))));
    xiB = fmaf(dt_c * a43, k3.y, fmaf(dt_c * a42, k2.y,
          fmaf(dt_c * a41, k1.y, fmaf(dt_c * a40, k0.y, xB))));
    k4 = eval_vf2(xiA, xiB, fmaf(c4c, dt_c, t), tid, W1p, W2p, w1t, b1, b2, sxi, sh);

    xiA = fmaf(dt_c * a54, k4.x, fmaf(dt_c * a53, k3.x, fmaf(dt_c * a52, k2.x,
          fmaf(dt_c * a51, k1.x, fmaf(dt_c * a50, k0.x, xA)))));
    xiB = fmaf(dt_c * a54, k4.y, fmaf(dt_c * a53, k3.y, fmaf(dt_c * a52, k2.y,
          fmaf(dt_c * a51, k1.y, fmaf(dt_c * a50, k0.y, xB)))));
    k5 = eval_vf2(xiA, xiB, t + dt_c, tid, W1p, W2p, w1t, b1, b2, sxi, sh);

    // stage-7 point == x5 (FSAL)
    float x5A = fmaf(dt_c * b55, k5.x, fmaf(dt_c * b54, k4.x, fmaf(dt_c * b53, k3.x,
                fmaf(dt_c * b52, k2.x, fmaf(dt_c * b50, k0.x, xA)))));
    float x5B = fmaf(dt_c * b55, k5.y, fmaf(dt_c * b54, k4.y, fmaf(dt_c * b53, k3.y,
                fmaf(dt_c * b52, k2.y, fmaf(dt_c * b50, k0.y, xB)))));
    k6 = eval_vf2(x5A, x5B, t + dt_c, tid, W1p, W2p, w1t, b1, b2, sxi, sh);

    // embedded error, global RMS over full batch
    float errA = fmaf(dt_c * d6, k6.x, fmaf(dt_c * d5, k5.x, fmaf(dt_c * d4, k4.x,
                 fmaf(dt_c * d3, k3.x, fmaf(dt_c * d2, k2.x, dt_c * d0 * k0.x)))));
    float errB = fmaf(dt_c * d6, k6.y, fmaf(dt_c * d5, k5.y, fmaf(dt_c * d4, k4.y,
                 fmaf(dt_c * d3, k3.y, fmaf(dt_c * d2, k2.y, dt_c * d0 * k0.y)))));
    float scA = fmaf(1e-3f, fmaxf(fabsf(xA), fabsf(x5A)), 1e-4f);
    float scB = fmaf(1e-3f, fmaxf(fabsf(xB), fabsf(x5B)), 1e-4f);
    float rA = errA / scA, rB = errB / scB;
    float loc = rA * rA + rB * rB;
#pragma unroll
    for (int o = 32; o > 0; o >>= 1) loc += __shfl_down(loc, o);
    if ((tid & 63) == 0) sred[tid >> 6] = loc;
    __syncthreads();
    if (tid == 0)
      atomicAdd(&errAcc[it], sred[0] + sred[1] + sred[2] + sred[3]);
    gridg.sync();

    float total = __hip_atomic_load(&errAcc[it], __ATOMIC_RELAXED,
                                    __HIP_MEMORY_SCOPE_AGENT);
    float err_norm = sqrtf(total * (1.0f / 65536.0f));
    bool accept = err_norm <= 1.0f;
    float factor = 0.9f * powf(err_norm + 1e-10f, -0.2f);
    factor = fminf(fmaxf(factor, 0.2f), 5.0f);
    if (accept) { t = t + dt_c; xA = x5A; xB = x5B; k0 = k6; }
    dt = dt_c * factor;
  }

  out[row0 * 256 + tid] = x0v0;
  out[(row0 + 1) * 256 + tid] = x0v1;
  out[65536 + row0 * 256 + tid] = xA;
  out[65536 + (row0 + 1) * 256 + tid] = xB;
}

extern "C" void kernel_launch(void* const* d_in, const int* in_sizes, int n_in,
                              void* d_out, int out_size, void* d_ws,
                              size_t ws_size, hipStream_t stream) {
  const float* x0 = (const float*)d_in[0];
  const float* W1 = (const float*)d_in[1];
  const float* b1 = (const float*)d_in[2];
  const float* W2 = (const float*)d_in[3];
  const float* b2 = (const float*)d_in[4];
  float* out = (float*)d_out;
  char* ws = (char*)d_ws;
  uint4* W1p = (uint4*)(ws + WS_W1P_OFF);
  uint4* W2p = (uint4*)(ws + WS_W2P_OFF);
  float* errAcc = (float*)(ws + WS_ERR_OFF);

  void* args[] = {&x0, &W1, &b1, &W2, &b2, &out, &W1p, &W2p, &errAcc};
  hipLaunchCooperativeKernel((void*)neural_ode_dopri5, dim3(128), dim3(256),
                             args, 0, stream);
}

// Round 3
// 483.226 us; speedup vs baseline: 1.0611x; 1.0611x over previous
//
#include <hip/hip_runtime.h>
#include <hip/hip_cooperative_groups.h>
#include <cstdint>

namespace cg = cooperative_groups;

// ---------------------------------------------------------------------------
// NeuralODE DoPri5 on MI355X — Round 3: LDS-resident weight slices.
// R2 post-mortem: bottleneck is per-CU L2 return BW (136 GB/s/CU); each WG
// streamed 1 MB weights/eval -> 7.3 us/eval regardless of #WGs. Fix: park
// weights in LDS. 32 groups x 8 WGs; group owns 8 batch rows; member m owns
// hidden slice [128m,128m+128) (W1/W2 f16 slices = 128 KB LDS, loaded once).
// Per stage: MFMA 16x16x32_f16 GEMM1+GEMM2, k-partials (8KB f32) exchanged
// via L2 + 8-WG device-scope phase barrier; controller via 32-group counter.
// ---------------------------------------------------------------------------

typedef _Float16 f16x8 __attribute__((ext_vector_type(8)));
typedef float f32x4 __attribute__((ext_vector_type(4)));

#define SMEM_BYTES 152640

// d_ws layout (needs ~2.01 MB)
#define BAR_OFF    (2u * 1024u * 1024u)   // 32 groups * 16 u32 (64B spaced)
#define ERRACC_OFF (BAR_OFF + 4096u)      // 64 f32
#define ERRCNT_OFF (ERRACC_OFF + 256u)    // 64 u32

extern "C" __global__ void __launch_bounds__(256, 1) neural_ode_dopri5(
    const float* __restrict__ x0g, const float* __restrict__ W1,
    const float* __restrict__ b1, const float* __restrict__ W2,
    const float* __restrict__ b2, float* __restrict__ out,
    float* __restrict__ part, unsigned* __restrict__ grpBar,
    float* __restrict__ errAcc, unsigned* __restrict__ errCnt) {
  cg::grid_group gridg = cg::this_grid();
  const int tid = threadIdx.x;
  const int bx = blockIdx.x;
  const int g = bx & 31;   // group: rows [8g, 8g+8)  (members share XCD: bx%8==g%8)
  const int m = bx >> 5;   // member: hidden slice [128m, 128m+128)
  const int w = tid >> 6, lane = tid & 63, n16 = lane & 15, q = lane >> 4;
  const int r = tid >> 5, fb = tid & 31;  // thread state: row r, features [8fb,8fb+8)

  // ---- LDS carve (dynamic, 149 KB) ---------------------------------------
  extern __shared__ char smem[];
  _Float16* W1s  = (_Float16*)smem;                  // [128 cols][264]  (k 0..255)
  _Float16* W2s  = (_Float16*)(smem + 67584);        // [256 cols][136]  (k 0..127)
  _Float16* xi_s = (_Float16*)(smem + 137216);       // [16 rows][264]
  _Float16* h_s  = (_Float16*)(smem + 145664);       // [16 rows][136]
  float* sw1t   = (float*)(smem + 150016);           // [128] time row slice
  float* sb1c   = sw1t + 128;                        // [128] b1 slice
  float* sbias1 = sb1c + 128;                        // [128] per-stage bias
  float* sb2    = sbias1 + 128;                      // [256]
  float* sred   = sb2 + 256;                         // [4]
  float* sbc    = sred + 4;                          // [1] broadcast

  // ---- prologue ----------------------------------------------------------
  if (bx == 0) {
    for (int i = tid; i < 512; i += 256) grpBar[i] = 0u;
    if (tid < 64) { errAcc[tid] = 0.0f; errCnt[tid] = 0u; }
  }
  // W1 slice -> LDS, transposed to [col][k] f16
  for (int kk = 0; kk < 128; ++kk) {
    const int k = 2 * kk + (tid >> 7), c = tid & 127;
    W1s[c * 264 + k] = (_Float16)W1[k * 1024 + m * 128 + c];
  }
  // W2 slice -> LDS [col][k] f16
  for (int kk = 0; kk < 128; ++kk)
    W2s[tid * 136 + kk] = (_Float16)W2[(m * 128 + kk) * 256 + tid];
  if (tid < 128) {
    sw1t[tid] = W1[256 * 1024 + m * 128 + tid];
    sb1c[tid] = b1[m * 128 + tid];
  }
  sb2[tid] = b2[tid];
  for (int i = tid; i < 16 * 264; i += 256) xi_s[i] = (_Float16)0.0f;
  for (int i = tid; i < 16 * 136; i += 256) h_s[i] = (_Float16)0.0f;
  gridg.sync();

  // ---- per-thread ODE state ----------------------------------------------
  const float* xrow = x0g + (8 * g + r) * 256 + fb * 8;
  float x[8];
  {
    float4 v0 = ((const float4*)xrow)[0], v1 = ((const float4*)xrow)[1];
    x[0] = v0.x; x[1] = v0.y; x[2] = v0.z; x[3] = v0.w;
    x[4] = v1.x; x[5] = v1.y; x[6] = v1.z; x[7] = v1.w;
  }
  float ks[7][8];
  unsigned phase = 0;

  // ---- one vf eval: xi(8 regs/thread) -> k(8 regs/thread) ----------------
  auto stage_eval = [&](const float* xi, float ti, float* kout) {
    ++phase;
    if (tid < 128) sbias1[tid] = fmaf(ti, sw1t[tid], sb1c[tid]);
    f16x8 xv;
#pragma unroll
    for (int j = 0; j < 8; ++j) xv[j] = (_Float16)xi[j];
    *(f16x8*)(xi_s + r * 264 + fb * 8) = xv;
    __syncthreads();

    // GEMM1: h_pre[16][128] = xi @ W1slice + bias1   (2 N-tiles per wave)
    f32x4 acc1[2];
#pragma unroll
    for (int tt = 0; tt < 2; ++tt) {
      const float bb = sbias1[(2 * w + tt) * 16 + n16];
      acc1[tt] = (f32x4){bb, bb, bb, bb};
    }
#pragma unroll
    for (int kk = 0; kk < 8; ++kk) {
      const f16x8 av = *(const f16x8*)(xi_s + n16 * 264 + kk * 32 + q * 8);
#pragma unroll
      for (int tt = 0; tt < 2; ++tt) {
        const f16x8 bv =
            *(const f16x8*)(W1s + ((2 * w + tt) * 16 + n16) * 264 + kk * 32 + q * 8);
        acc1[tt] = __builtin_amdgcn_mfma_f32_16x16x32_f16(av, bv, acc1[tt], 0, 0, 0);
      }
    }
#pragma unroll
    for (int tt = 0; tt < 2; ++tt) {
      const int c = (2 * w + tt) * 16 + n16;
#pragma unroll
      for (int reg = 0; reg < 4; ++reg)
        h_s[(q * 4 + reg) * 136 + c] = (_Float16)tanhf(acc1[tt][reg]);
    }
    __syncthreads();

    // GEMM2 partial: kp[16][256] = h @ W2slice (+ b2 on member 0)
    f32x4 acc2[4];
#pragma unroll
    for (int tt = 0; tt < 4; ++tt) {
      const float bb = (m == 0) ? sb2[(w * 4 + tt) * 16 + n16] : 0.0f;
      acc2[tt] = (f32x4){bb, bb, bb, bb};
    }
#pragma unroll
    for (int kk = 0; kk < 4; ++kk) {
      const f16x8 av = *(const f16x8*)(h_s + n16 * 136 + kk * 32 + q * 8);
#pragma unroll
      for (int tt = 0; tt < 4; ++tt) {
        const f16x8 bv =
            *(const f16x8*)(W2s + ((w * 4 + tt) * 16 + n16) * 136 + kk * 32 + q * 8);
        acc2[tt] = __builtin_amdgcn_mfma_f32_16x16x32_f16(av, bv, acc2[tt], 0, 0, 0);
      }
    }
    // store partial rows 0..7 (rows 8-15 of the M=16 tile are padding)
    float* pbase = part + bx * 2048;
    if (q < 2) {
#pragma unroll
      for (int tt = 0; tt < 4; ++tt) {
        const int c = (w * 4 + tt) * 16 + n16;
#pragma unroll
        for (int reg = 0; reg < 4; ++reg)
          pbase[(q * 4 + reg) * 256 + c] = acc2[tt][reg];
      }
    }
    __syncthreads();  // each wave drains vmcnt before barrier
    if (tid == 0) {
      __hip_atomic_fetch_add(&grpBar[g * 16], 1u, __ATOMIC_ACQ_REL,
                             __HIP_MEMORY_SCOPE_AGENT);
      const unsigned target = 8u * phase;
      while (__hip_atomic_load(&grpBar[g * 16], __ATOMIC_ACQUIRE,
                               __HIP_MEMORY_SCOPE_AGENT) < target) {}
    }
    __syncthreads();
    // gather + reduce the 8 members' partials for this thread's 8 elements
    float k0 = 0, k1 = 0, k2 = 0, k3 = 0, k4 = 0, k5 = 0, k6 = 0, k7 = 0;
#pragma unroll
    for (int mm = 0; mm < 8; ++mm) {
      const float4* pp =
          (const float4*)(part + (mm * 32 + g) * 2048 + r * 256 + fb * 8);
      float4 v0 = pp[0], v1 = pp[1];
      k0 += v0.x; k1 += v0.y; k2 += v0.z; k3 += v0.w;
      k4 += v1.x; k5 += v1.y; k6 += v1.z; k7 += v1.w;
    }
    kout[0] = k0; kout[1] = k1; kout[2] = k2; kout[3] = k3;
    kout[4] = k4; kout[5] = k5; kout[6] = k6; kout[7] = k7;
  };

  // ---- Butcher tableau ----------------------------------------------------
  const float AB[6][6] = {
      {(float)(1.0 / 5.0), 0, 0, 0, 0, 0},
      {(float)(3.0 / 40.0), (float)(9.0 / 40.0), 0, 0, 0, 0},
      {(float)(44.0 / 45.0), (float)(-56.0 / 15.0), (float)(32.0 / 9.0), 0, 0, 0},
      {(float)(19372.0 / 6561.0), (float)(-25360.0 / 2187.0),
       (float)(64448.0 / 6561.0), (float)(-212.0 / 729.0), 0, 0},
      {(float)(9017.0 / 3168.0), (float)(-355.0 / 33.0),
       (float)(46732.0 / 5247.0), (float)(49.0 / 176.0),
       (float)(-5103.0 / 18656.0), 0},
      {(float)(35.0 / 384.0), 0.0f, (float)(500.0 / 1113.0),
       (float)(125.0 / 192.0), (float)(-2187.0 / 6784.0), (float)(11.0 / 84.0)}};
  const float CC[7] = {0.0f, (float)(1.0 / 5.0), (float)(3.0 / 10.0),
                       (float)(4.0 / 5.0), (float)(8.0 / 9.0), 1.0f, 1.0f};
  const float DD[7] = {(float)(35.0 / 384.0 - 5179.0 / 57600.0), 0.0f,
                       (float)(500.0 / 1113.0 - 7571.0 / 16695.0),
                       (float)(125.0 / 192.0 - 393.0 / 640.0),
                       (float)(-2187.0 / 6784.0 + 92097.0 / 339200.0),
                       (float)(11.0 / 84.0 - 187.0 / 2100.0),
                       (float)(-1.0 / 40.0)};

  float t = 0.0f, dt = 0.05f;
  stage_eval(x, 0.0f, ks[0]);  // FSAL seed: k0 = f(x0, 0)

  for (int it = 0; it < 64; ++it) {
    if (t >= 1.0f) break;  // controller is globally uniform -> exact
    const float dt_c = fmaxf(fminf(dt, 1.0f - t), 0.0f);

    float x5[8];
#pragma unroll
    for (int s = 1; s <= 6; ++s) {
      float xi[8];
#pragma unroll
      for (int j = 0; j < 8; ++j) {
        float v = x[j];
#pragma unroll
        for (int p = 0; p < 6; ++p)
          if (p < s) v = fmaf(dt_c * AB[s - 1][p], ks[p][j], v);
        xi[j] = v;
        if (s == 6) x5[j] = v;  // stage-7 point == x5 (FSAL)
      }
      stage_eval(xi, fmaf(CC[s], dt_c, t), ks[s]);
    }

    // embedded error -> global RMS across all 256 rows
    float loc = 0.0f;
#pragma unroll
    for (int j = 0; j < 8; ++j) {
      float e = 0.0f;
#pragma unroll
      for (int s = 0; s < 7; ++s) e = fmaf(dt_c * DD[s], ks[s][j], e);
      const float scale = fmaf(1e-3f, fmaxf(fabsf(x[j]), fabsf(x5[j])), 1e-4f);
      const float rr = e / scale;
      loc = fmaf(rr, rr, loc);
    }
#pragma unroll
    for (int o = 32; o > 0; o >>= 1) loc += __shfl_down(loc, o);
    if (lane == 0) sred[w] = loc;
    __syncthreads();
    if (tid == 0) {
      if (m == 0) {
        atomicAdd(&errAcc[it], sred[0] + sred[1] + sred[2] + sred[3]);
        __hip_atomic_fetch_add(&errCnt[it], 1u, __ATOMIC_RELEASE,
                               __HIP_MEMORY_SCOPE_AGENT);
      }
      while (__hip_atomic_load(&errCnt[it], __ATOMIC_ACQUIRE,
                               __HIP_MEMORY_SCOPE_AGENT) < 32u) {}
      sbc[0] = __hip_atomic_load(&errAcc[it], __ATOMIC_RELAXED,
                                 __HIP_MEMORY_SCOPE_AGENT);
    }
    __syncthreads();
    const float err_norm = sqrtf(sbc[0] * (1.0f / 65536.0f));
    const bool accept = err_norm <= 1.0f;
    float factor = 0.9f * powf(err_norm + 1e-10f, -0.2f);
    factor = fminf(fmaxf(factor, 0.2f), 5.0f);
    if (accept) {
      t = t + dt_c;
#pragma unroll
      for (int j = 0; j < 8; ++j) { x[j] = x5[j]; ks[0][j] = ks[6][j]; }
    }
    dt = dt_c * factor;
    __syncthreads();  // sbc reuse guard
  }

  // ---- output: stack([x0, xf]) (member 0 only) ---------------------------
  if (m == 0) {
    float4* o0 = (float4*)(out + (8 * g + r) * 256 + fb * 8);
    const float4* xr = (const float4*)xrow;
    o0[0] = xr[0]; o0[1] = xr[1];
    float4 a0, a1;
    a0.x = x[0]; a0.y = x[1]; a0.z = x[2]; a0.w = x[3];
    a1.x = x[4]; a1.y = x[5]; a1.z = x[6]; a1.w = x[7];
    float4* o1 = (float4*)(out + 65536 + (8 * g + r) * 256 + fb * 8);
    o1[0] = a0; o1[1] = a1;
  }
}

extern "C" void kernel_launch(void* const* d_in, const int* in_sizes, int n_in,
                              void* d_out, int out_size, void* d_ws,
                              size_t ws_size, hipStream_t stream) {
  const float* x0 = (const float*)d_in[0];
  const float* W1 = (const float*)d_in[1];
  const float* b1 = (const float*)d_in[2];
  const float* W2 = (const float*)d_in[3];
  const float* b2 = (const float*)d_in[4];
  float* out = (float*)d_out;
  char* ws = (char*)d_ws;
  float* part = (float*)ws;
  unsigned* grpBar = (unsigned*)(ws + BAR_OFF);
  float* errAcc = (float*)(ws + ERRACC_OFF);
  unsigned* errCnt = (unsigned*)(ws + ERRCNT_OFF);

  hipFuncSetAttribute((const void*)neural_ode_dopri5,
                      hipFuncAttributeMaxDynamicSharedMemorySize, SMEM_BYTES);

  void* args[] = {&x0, &W1, &b1, &W2, &b2, &out, &part, &grpBar, &errAcc, &errCnt};
  hipLaunchCooperativeKernel((void*)neural_ode_dopri5, dim3(256), dim3(256),
                             args, SMEM_BYTES, stream);
}

// Round 4
// 238.835 us; speedup vs baseline: 2.1469x; 2.0233x over previous
//
#include <hip/hip_runtime.h>
#include <hip/hip_cooperative_groups.h>
#include <cstdint>

namespace cg = cooperative_groups;

// ---------------------------------------------------------------------------
// NeuralODE DoPri5 on MI355X — Round 4: fence-free inter-WG exchange.
// R3 post-mortem: agent-scope acq/rel around the per-stage barrier lowers to
// buffer_wbl2 + inv on gfx950 (non-coherent per-XCD L2s) -> full L2 flush per
// WG per stage (WRITE_SIZE 52 MB) ≈ 5 us/stage. Fix: no fences at all —
// partials move via RELAXED agent-scope atomics (sc0/sc1 write-through /
// cache-bypass), ordering from __syncthreads' vmcnt(0) drain + relaxed
// counter barrier. Partials in f16, double-buffered by phase parity.
// Controller: sentinel-slot allgather (relaxed), no acquire polls.
// Weights stay LDS-resident (R3 structure, verified): 32 groups x 8 WGs,
// member m owns hidden slice [128m,128m+128); MFMA 16x16x32_f16.
// ---------------------------------------------------------------------------

typedef _Float16 f16x8 __attribute__((ext_vector_type(8)));
typedef float f32x4 __attribute__((ext_vector_type(4)));

#define SMEM_BYTES 152640

// d_ws layout: [0,2MB) f16 partials (2 bufs x 256 WG x 4KB) | 2MB: grpBar | +4KB: errSlots
#define BAR_OFF  (2u * 1024u * 1024u)
#define SLOT_OFF (BAR_OFF + 4096u)

union U64H4 { unsigned long long u; _Float16 h[4]; };

__device__ __forceinline__ float fast_tanh(float v) {
  // tanh(v) = 1 - 2/(exp2(2*log2(e)*v) + 1); saturates correctly at +-inf
  float e = __builtin_amdgcn_exp2f(v * 2.88539008177793f);
  return fmaf(-2.0f, __builtin_amdgcn_rcpf(e + 1.0f), 1.0f);
}

extern "C" __global__ void __launch_bounds__(256, 1) neural_ode_dopri5(
    const float* __restrict__ x0g, const float* __restrict__ W1,
    const float* __restrict__ b1, const float* __restrict__ W2,
    const float* __restrict__ b2, float* __restrict__ out,
    unsigned long long* __restrict__ partB, unsigned* __restrict__ grpBar,
    float* __restrict__ errSlots) {
  cg::grid_group gridg = cg::this_grid();
  const int tid = threadIdx.x;
  const int bx = blockIdx.x;
  const int g = bx & 31;   // group: rows [8g, 8g+8)
  const int m = bx >> 5;   // member: hidden slice [128m, 128m+128)
  const int w = tid >> 6, lane = tid & 63, n16 = lane & 15, q = lane >> 4;
  const int r = tid >> 5, fb = tid & 31;  // thread state: row r, feats [8fb,8fb+8)

  // ---- LDS carve (dynamic, ~149 KB) --------------------------------------
  extern __shared__ char smem[];
  _Float16* W1s  = (_Float16*)smem;                  // [128 cols][264]
  _Float16* W2s  = (_Float16*)(smem + 67584);        // [256 cols][136]
  _Float16* xi_s = (_Float16*)(smem + 137216);       // [16 rows][264]; rows0-7 reused as stag
  _Float16* h_s  = (_Float16*)(smem + 145664);       // [16 rows][136]
  float* sw1t   = (float*)(smem + 150016);           // [128]
  float* sb1c   = sw1t + 128;                        // [128]
  float* sbias1 = sb1c + 128;                        // [128]
  float* sb2    = sbias1 + 128;                      // [256]
  float* sred   = sb2 + 256;                         // [4]

  // ---- prologue ----------------------------------------------------------
  if (bx == 0) {
    for (int i = tid; i < 512; i += 256) grpBar[i] = 0u;
    for (int i = tid; i < 2048; i += 256) errSlots[i] = -1.0f;  // sentinel
  }
  for (int kk = 0; kk < 128; ++kk) {
    const int k = 2 * kk + (tid >> 7), c = tid & 127;
    W1s[c * 264 + k] = (_Float16)W1[k * 1024 + m * 128 + c];
  }
  for (int kk = 0; kk < 128; ++kk)
    W2s[tid * 136 + kk] = (_Float16)W2[(m * 128 + kk) * 256 + tid];
  if (tid < 128) {
    sw1t[tid] = W1[256 * 1024 + m * 128 + tid];
    sb1c[tid] = b1[m * 128 + tid];
  }
  sb2[tid] = b2[tid];
  for (int i = tid; i < 16 * 264; i += 256) xi_s[i] = (_Float16)0.0f;
  for (int i = tid; i < 16 * 136; i += 256) h_s[i] = (_Float16)0.0f;
  gridg.sync();

  // ---- per-thread ODE state ----------------------------------------------
  const float* xrow = x0g + (8 * g + r) * 256 + fb * 8;
  float x[8];
  {
    float4 v0 = ((const float4*)xrow)[0], v1 = ((const float4*)xrow)[1];
    x[0] = v0.x; x[1] = v0.y; x[2] = v0.z; x[3] = v0.w;
    x[4] = v1.x; x[5] = v1.y; x[6] = v1.z; x[7] = v1.w;
  }
  float ks[7][8];
  unsigned phase = 0;

  // ---- one vf eval: xi(8 regs/thread) -> k(8 regs/thread) ----------------
  auto stage_eval = [&](const float* xi, float ti, float* kout) {
    ++phase;
    const unsigned buf = phase & 1u;
    if (tid < 128) sbias1[tid] = fmaf(ti, sw1t[tid], sb1c[tid]);
    f16x8 xv;
#pragma unroll
    for (int j = 0; j < 8; ++j) xv[j] = (_Float16)xi[j];
    *(f16x8*)(xi_s + r * 264 + fb * 8) = xv;
    __syncthreads();

    // GEMM1: h_pre[16][128] = xi @ W1slice + bias1
    f32x4 acc1[2];
#pragma unroll
    for (int tt = 0; tt < 2; ++tt) {
      const float bb = sbias1[(2 * w + tt) * 16 + n16];
      acc1[tt] = (f32x4){bb, bb, bb, bb};
    }
#pragma unroll
    for (int kk = 0; kk < 8; ++kk) {
      const f16x8 av = *(const f16x8*)(xi_s + n16 * 264 + kk * 32 + q * 8);
#pragma unroll
      for (int tt = 0; tt < 2; ++tt) {
        const f16x8 bv =
            *(const f16x8*)(W1s + ((2 * w + tt) * 16 + n16) * 264 + kk * 32 + q * 8);
        acc1[tt] = __builtin_amdgcn_mfma_f32_16x16x32_f16(av, bv, acc1[tt], 0, 0, 0);
      }
    }
#pragma unroll
    for (int tt = 0; tt < 2; ++tt) {
      const int c = (2 * w + tt) * 16 + n16;
#pragma unroll
      for (int reg = 0; reg < 4; ++reg)
        h_s[(q * 4 + reg) * 136 + c] = (_Float16)fast_tanh(acc1[tt][reg]);
    }
    __syncthreads();

    // GEMM2 partial: kp[16][256] = h @ W2slice (bias added by reader)
    f32x4 acc2[4];
#pragma unroll
    for (int tt = 0; tt < 4; ++tt) acc2[tt] = (f32x4){0.f, 0.f, 0.f, 0.f};
#pragma unroll
    for (int kk = 0; kk < 4; ++kk) {
      const f16x8 av = *(const f16x8*)(h_s + n16 * 136 + kk * 32 + q * 8);
#pragma unroll
      for (int tt = 0; tt < 4; ++tt) {
        const f16x8 bv =
            *(const f16x8*)(W2s + ((w * 4 + tt) * 16 + n16) * 136 + kk * 32 + q * 8);
        acc2[tt] = __builtin_amdgcn_mfma_f32_16x16x32_f16(av, bv, acc2[tt], 0, 0, 0);
      }
    }
    // transpose fragments -> row-major f16 staging in LDS (reuse xi_s rows0-7)
    _Float16* stag = xi_s;
    if (q < 2) {
#pragma unroll
      for (int tt = 0; tt < 4; ++tt) {
        const int c = (w * 4 + tt) * 16 + n16;
#pragma unroll
        for (int reg = 0; reg < 4; ++reg)
          stag[(q * 4 + reg) * 264 + c] = (_Float16)acc2[tt][reg];
      }
    }
    __syncthreads();
    // publish: 16 B per thread, relaxed agent stores (write-through, no fence)
    {
      const unsigned long long* srcp =
          (const unsigned long long*)(stag + r * 264 + fb * 8);
      unsigned long long u0 = srcp[0], u1 = srcp[1];
      unsigned long long* dst =
          partB + (buf << 17) + (bx << 9) + (r << 6) + (fb << 1);
      __hip_atomic_store(dst, u0, __ATOMIC_RELAXED, __HIP_MEMORY_SCOPE_AGENT);
      __hip_atomic_store(dst + 1, u1, __ATOMIC_RELAXED, __HIP_MEMORY_SCOPE_AGENT);
    }
    __syncthreads();  // drains vmcnt(0): all WG stores globally visible
    if (tid == 0)
      __hip_atomic_fetch_add(&grpBar[g * 16], 1u, __ATOMIC_RELAXED,
                             __HIP_MEMORY_SCOPE_AGENT);
    const unsigned target = 8u * phase;
    while (__hip_atomic_load(&grpBar[g * 16], __ATOMIC_RELAXED,
                             __HIP_MEMORY_SCOPE_AGENT) < target) {}
    // gather + reduce 8 members' f16 partials (+b2), relaxed agent loads
    float kacc[8];
    {
      const float4* sb2v = (const float4*)(sb2 + fb * 8);
      float4 bA = sb2v[0], bB = sb2v[1];
      kacc[0] = bA.x; kacc[1] = bA.y; kacc[2] = bA.z; kacc[3] = bA.w;
      kacc[4] = bB.x; kacc[5] = bB.y; kacc[6] = bB.z; kacc[7] = bB.w;
    }
    const int gbase = (buf << 17) + (r << 6) + (fb << 1);
#pragma unroll
    for (int mm = 0; mm < 8; ++mm) {
      const unsigned long long* pp = partB + gbase + ((mm * 32 + g) << 9);
      U64H4 ua, ub;
      ua.u = __hip_atomic_load(pp, __ATOMIC_RELAXED, __HIP_MEMORY_SCOPE_AGENT);
      ub.u = __hip_atomic_load(pp + 1, __ATOMIC_RELAXED, __HIP_MEMORY_SCOPE_AGENT);
#pragma unroll
      for (int j = 0; j < 4; ++j) {
        kacc[j] += (float)ua.h[j];
        kacc[4 + j] += (float)ub.h[j];
      }
    }
#pragma unroll
    for (int j = 0; j < 8; ++j) kout[j] = kacc[j];
  };

  // ---- Butcher tableau ----------------------------------------------------
  const float AB[6][6] = {
      {(float)(1.0 / 5.0), 0, 0, 0, 0, 0},
      {(float)(3.0 / 40.0), (float)(9.0 / 40.0), 0, 0, 0, 0},
      {(float)(44.0 / 45.0), (float)(-56.0 / 15.0), (float)(32.0 / 9.0), 0, 0, 0},
      {(float)(19372.0 / 6561.0), (float)(-25360.0 / 2187.0),
       (float)(64448.0 / 6561.0), (float)(-212.0 / 729.0), 0, 0},
      {(float)(9017.0 / 3168.0), (float)(-355.0 / 33.0),
       (float)(46732.0 / 5247.0), (float)(49.0 / 176.0),
       (float)(-5103.0 / 18656.0), 0},
      {(float)(35.0 / 384.0), 0.0f, (float)(500.0 / 1113.0),
       (float)(125.0 / 192.0), (float)(-2187.0 / 6784.0), (float)(11.0 / 84.0)}};
  const float CC[7] = {0.0f, (float)(1.0 / 5.0), (float)(3.0 / 10.0),
                       (float)(4.0 / 5.0), (float)(8.0 / 9.0), 1.0f, 1.0f};
  const float DD[7] = {(float)(35.0 / 384.0 - 5179.0 / 57600.0), 0.0f,
                       (float)(500.0 / 1113.0 - 7571.0 / 16695.0),
                       (float)(125.0 / 192.0 - 393.0 / 640.0),
                       (float)(-2187.0 / 6784.0 + 92097.0 / 339200.0),
                       (float)(11.0 / 84.0 - 187.0 / 2100.0),
                       (float)(-1.0 / 40.0)};

  float t = 0.0f, dt = 0.05f;
  stage_eval(x, 0.0f, ks[0]);  // FSAL seed

  for (int it = 0; it < 64; ++it) {
    if (t >= 1.0f) break;  // controller is globally uniform -> exact
    const float dt_c = fmaxf(fminf(dt, 1.0f - t), 0.0f);

    float x5[8];
#pragma unroll
    for (int s = 1; s <= 6; ++s) {
      float xi[8];
#pragma unroll
      for (int j = 0; j < 8; ++j) {
        float v = x[j];
#pragma unroll
        for (int p = 0; p < 6; ++p)
          if (p < s) v = fmaf(dt_c * AB[s - 1][p], ks[p][j], v);
        xi[j] = v;
        if (s == 6) x5[j] = v;  // stage-7 point == x5 (FSAL)
      }
      stage_eval(xi, fmaf(CC[s], dt_c, t), ks[s]);
    }

    // member 0 of each group publishes its group's err sum to a slot
    if (m == 0) {
      float loc = 0.0f;
#pragma unroll
      for (int j = 0; j < 8; ++j) {
        float e = 0.0f;
#pragma unroll
        for (int s = 0; s < 7; ++s) e = fmaf(dt_c * DD[s], ks[s][j], e);
        const float scale = fmaf(1e-3f, fmaxf(fabsf(x[j]), fabsf(x5[j])), 1e-4f);
        const float rr = e / scale;
        loc = fmaf(rr, rr, loc);
      }
#pragma unroll
      for (int o = 32; o > 0; o >>= 1) loc += __shfl_down(loc, o);
      if (lane == 0) sred[w] = loc;
      __syncthreads();
      if (tid == 0) {
        const float s4 = sred[0] + sred[1] + sred[2] + sred[3];
        __hip_atomic_store(&errSlots[it * 32 + g], s4, __ATOMIC_RELAXED,
                           __HIP_MEMORY_SCOPE_AGENT);
      }
    }
    // all threads spin-sum the 32 slots (sentinel -1 until written)
    float total;
    for (;;) {
      total = 0.0f;
      bool ok = true;
#pragma unroll 4
      for (int gg = 0; gg < 32; ++gg) {
        const float v = __hip_atomic_load(&errSlots[it * 32 + gg],
                                          __ATOMIC_RELAXED,
                                          __HIP_MEMORY_SCOPE_AGENT);
        ok &= (v >= 0.0f);
        total += v;
      }
      if (ok) break;
    }
    const float err_norm = sqrtf(total * (1.0f / 65536.0f));
    const bool accept = err_norm <= 1.0f;
    float factor = 0.9f * powf(err_norm + 1e-10f, -0.2f);
    factor = fminf(fmaxf(factor, 0.2f), 5.0f);
    if (accept) {
      t = t + dt_c;
#pragma unroll
      for (int j = 0; j < 8; ++j) { x[j] = x5[j]; ks[0][j] = ks[6][j]; }
    }
    dt = dt_c * factor;
  }

  // ---- output: stack([x0, xf]) (member 0 only) ---------------------------
  if (m == 0) {
    float4* o0 = (float4*)(out + (8 * g + r) * 256 + fb * 8);
    const float4* xr = (const float4*)xrow;
    o0[0] = xr[0]; o0[1] = xr[1];
    float4 a0, a1;
    a0.x = x[0]; a0.y = x[1]; a0.z = x[2]; a0.w = x[3];
    a1.x = x[4]; a1.y = x[5]; a1.z = x[6]; a1.w = x[7];
    float4* o1 = (float4*)(out + 65536 + (8 * g + r) * 256 + fb * 8);
    o1[0] = a0; o1[1] = a1;
  }
}

extern "C" void kernel_launch(void* const* d_in, const int* in_sizes, int n_in,
                              void* d_out, int out_size, void* d_ws,
                              size_t ws_size, hipStream_t stream) {
  const float* x0 = (const float*)d_in[0];
  const float* W1 = (const float*)d_in[1];
  const float* b1 = (const float*)d_in[2];
  const float* W2 = (const float*)d_in[3];
  const float* b2 = (const float*)d_in[4];
  float* out = (float*)d_out;
  char* ws = (char*)d_ws;
  unsigned long long* partB = (unsigned long long*)ws;
  unsigned* grpBar = (unsigned*)(ws + BAR_OFF);
  float* errSlots = (float*)(ws + SLOT_OFF);

  hipFuncSetAttribute((const void*)neural_ode_dopri5,
                      hipFuncAttributeMaxDynamicSharedMemorySize, SMEM_BYTES);

  void* args[] = {&x0, &W1, &b1, &W2, &b2, &out, &partB, &grpBar, &errSlots};
  hipLaunchCooperativeKernel((void*)neural_ode_dopri5, dim3(256), dim3(256),
                             args, SMEM_BYTES, stream);
}

// Round 5
// 208.553 us; speedup vs baseline: 2.4586x; 1.1452x over previous
//
#include <hip/hip_runtime.h>
#include <hip/hip_cooperative_groups.h>
#include <cstdint>

namespace cg = cooperative_groups;

// ---------------------------------------------------------------------------
// NeuralODE DoPri5 on MI355X — Round 5: stamp-based fence-free exchange.
// R4 post-mortem: 2.95 us/stage = 4 serialized coherence-point round trips
// (drain, fetch_add, spin, gather); compute only ~0.3 us. This round removes
// the counter barrier: writers publish data, drain (vmcnt0 via syncthreads),
// then store a per-(group,member) STAMP = phase. Stamp visibility implies
// data visibility (same ordering R4 relied on). Readers: wave0 lanes0-7 poll
// the group's 8-stamp 64B line (low congestion), then the WG gathers.
// Controller: wave0-only poll of 32 slots + LDS broadcast.
// Weights stay LDS-resident: 32 groups x 8 WGs, member m owns hidden slice
// [128m,128m+128); MFMA 16x16x32_f16; partials f16, double-buffered.
// ---------------------------------------------------------------------------

typedef _Float16 f16x8 __attribute__((ext_vector_type(8)));
typedef float f32x4 __attribute__((ext_vector_type(4)));

#define SMEM_BYTES 152640

// d_ws layout: [0,2MB) f16 partials (2 bufs x 256 WG x 4KB)
//              2MB: stamps (32 groups x 16 u32, 64B/group) | +4KB: errSlots
#define STAMP_OFF (2u * 1024u * 1024u)
#define SLOT_OFF  (STAMP_OFF + 4096u)

union U64H4 { unsigned long long u; _Float16 h[4]; };

__device__ __forceinline__ float fast_tanh(float v) {
  float e = __builtin_amdgcn_exp2f(v * 2.88539008177793f);
  return fmaf(-2.0f, __builtin_amdgcn_rcpf(e + 1.0f), 1.0f);
}

extern "C" __global__ void __launch_bounds__(256, 1) neural_ode_dopri5(
    const float* __restrict__ x0g, const float* __restrict__ W1,
    const float* __restrict__ b1, const float* __restrict__ W2,
    const float* __restrict__ b2, float* __restrict__ out,
    unsigned long long* __restrict__ partB, unsigned* __restrict__ stamps,
    float* __restrict__ errSlots) {
  cg::grid_group gridg = cg::this_grid();
  const int tid = threadIdx.x;
  const int bx = blockIdx.x;
  const int g = bx & 31;   // group: rows [8g, 8g+8)
  const int m = bx >> 5;   // member: hidden slice [128m, 128m+128)
  const int w = tid >> 6, lane = tid & 63, n16 = lane & 15, q = lane >> 4;
  const int r = tid >> 5, fb = tid & 31;  // thread state: row r, feats [8fb,8fb+8)

  // ---- LDS carve (dynamic, ~149 KB) --------------------------------------
  extern __shared__ char smem[];
  _Float16* W1s  = (_Float16*)smem;                  // [128 cols][264]
  _Float16* W2s  = (_Float16*)(smem + 67584);        // [256 cols][136]
  _Float16* xi_s = (_Float16*)(smem + 137216);       // [16 rows][264]; rows0-7 reused as stag
  _Float16* h_s  = (_Float16*)(smem + 145664);       // [16 rows][136]
  float* sw1t   = (float*)(smem + 150016);           // [128]
  float* sb1c   = sw1t + 128;                        // [128]
  float* sbias1 = sb1c + 128;                        // [128]
  float* sb2    = sbias1 + 128;                      // [256]
  float* sred   = sb2 + 256;                         // [4]
  float* sbc    = sred + 4;                          // [1] controller broadcast

  // ---- prologue ----------------------------------------------------------
  if (bx == 0) {
    for (int i = tid; i < 512; i += 256) stamps[i] = 0u;   // MUST be < 1
    for (int i = tid; i < 2048; i += 256) errSlots[i] = -1.0f;  // sentinel
  }
  for (int kk = 0; kk < 128; ++kk) {
    const int k = 2 * kk + (tid >> 7), c = tid & 127;
    W1s[c * 264 + k] = (_Float16)W1[k * 1024 + m * 128 + c];
  }
  for (int kk = 0; kk < 128; ++kk)
    W2s[tid * 136 + kk] = (_Float16)W2[(m * 128 + kk) * 256 + tid];
  if (tid < 128) {
    sw1t[tid] = W1[256 * 1024 + m * 128 + tid];
    sb1c[tid] = b1[m * 128 + tid];
  }
  sb2[tid] = b2[tid];
  for (int i = tid; i < 16 * 264; i += 256) xi_s[i] = (_Float16)0.0f;
  for (int i = tid; i < 16 * 136; i += 256) h_s[i] = (_Float16)0.0f;
  gridg.sync();

  // ---- per-thread ODE state ----------------------------------------------
  const float* xrow = x0g + (8 * g + r) * 256 + fb * 8;
  float x[8];
  {
    float4 v0 = ((const float4*)xrow)[0], v1 = ((const float4*)xrow)[1];
    x[0] = v0.x; x[1] = v0.y; x[2] = v0.z; x[3] = v0.w;
    x[4] = v1.x; x[5] = v1.y; x[6] = v1.z; x[7] = v1.w;
  }
  float ks[7][8];
  unsigned phase = 0;

  // ---- one vf eval: xi(8 regs/thread) -> k(8 regs/thread) ----------------
  auto stage_eval = [&](const float* xi, float ti, float* kout) {
    ++phase;
    const unsigned buf = phase & 1u;
    if (tid < 128) sbias1[tid] = fmaf(ti, sw1t[tid], sb1c[tid]);
    f16x8 xv;
#pragma unroll
    for (int j = 0; j < 8; ++j) xv[j] = (_Float16)xi[j];
    *(f16x8*)(xi_s + r * 264 + fb * 8) = xv;
    __syncthreads();

    // GEMM1: h_pre[16][128] = xi @ W1slice + bias1
    f32x4 acc1[2];
#pragma unroll
    for (int tt = 0; tt < 2; ++tt) {
      const float bb = sbias1[(2 * w + tt) * 16 + n16];
      acc1[tt] = (f32x4){bb, bb, bb, bb};
    }
#pragma unroll
    for (int kk = 0; kk < 8; ++kk) {
      const f16x8 av = *(const f16x8*)(xi_s + n16 * 264 + kk * 32 + q * 8);
#pragma unroll
      for (int tt = 0; tt < 2; ++tt) {
        const f16x8 bv =
            *(const f16x8*)(W1s + ((2 * w + tt) * 16 + n16) * 264 + kk * 32 + q * 8);
        acc1[tt] = __builtin_amdgcn_mfma_f32_16x16x32_f16(av, bv, acc1[tt], 0, 0, 0);
      }
    }
#pragma unroll
    for (int tt = 0; tt < 2; ++tt) {
      const int c = (2 * w + tt) * 16 + n16;
#pragma unroll
      for (int reg = 0; reg < 4; ++reg)
        h_s[(q * 4 + reg) * 136 + c] = (_Float16)fast_tanh(acc1[tt][reg]);
    }
    __syncthreads();

    // GEMM2 partial: kp[16][256] = h @ W2slice (bias added by reader)
    f32x4 acc2[4];
#pragma unroll
    for (int tt = 0; tt < 4; ++tt) acc2[tt] = (f32x4){0.f, 0.f, 0.f, 0.f};
#pragma unroll
    for (int kk = 0; kk < 4; ++kk) {
      const f16x8 av = *(const f16x8*)(h_s + n16 * 136 + kk * 32 + q * 8);
#pragma unroll
      for (int tt = 0; tt < 4; ++tt) {
        const f16x8 bv =
            *(const f16x8*)(W2s + ((w * 4 + tt) * 16 + n16) * 136 + kk * 32 + q * 8);
        acc2[tt] = __builtin_amdgcn_mfma_f32_16x16x32_f16(av, bv, acc2[tt], 0, 0, 0);
      }
    }
    // transpose fragments -> row-major f16 staging in LDS (reuse xi_s rows0-7)
    _Float16* stag = xi_s;
    if (q < 2) {
#pragma unroll
      for (int tt = 0; tt < 4; ++tt) {
        const int c = (w * 4 + tt) * 16 + n16;
#pragma unroll
        for (int reg = 0; reg < 4; ++reg)
          stag[(q * 4 + reg) * 264 + c] = (_Float16)acc2[tt][reg];
      }
    }
    __syncthreads();
    // publish: 16 B per thread, relaxed agent stores (write-through, no fence)
    {
      const unsigned long long* srcp =
          (const unsigned long long*)(stag + r * 264 + fb * 8);
      unsigned long long u0 = srcp[0], u1 = srcp[1];
      unsigned long long* dst =
          partB + (buf << 17) + (bx << 9) + (r << 6) + (fb << 1);
      __hip_atomic_store(dst, u0, __ATOMIC_RELAXED, __HIP_MEMORY_SCOPE_AGENT);
      __hip_atomic_store(dst + 1, u1, __ATOMIC_RELAXED, __HIP_MEMORY_SCOPE_AGENT);
    }
    __syncthreads();  // vmcnt(0) per wave: all WG data stores acked/visible
    // stamp: visibility of (stamp == phase) implies this member's data is
    // visible (data stores were drained before the stamp store issued).
    if (tid == 0)
      __hip_atomic_store(&stamps[g * 16 + m], phase, __ATOMIC_RELAXED,
                         __HIP_MEMORY_SCOPE_AGENT);
    // wave 0, lanes 0..7 poll the group's 8-stamp line; others idle at barrier
    if (w == 0) {
      for (;;) {
        unsigned v = phase;
        if (lane < 8)
          v = __hip_atomic_load(&stamps[g * 16 + lane], __ATOMIC_RELAXED,
                                __HIP_MEMORY_SCOPE_AGENT);
        if (__all(v >= phase)) break;
      }
    }
    __syncthreads();
    // gather + reduce 8 members' f16 partials (+b2), relaxed agent loads
    float kacc[8];
    {
      const float4* sb2v = (const float4*)(sb2 + fb * 8);
      float4 bA = sb2v[0], bB = sb2v[1];
      kacc[0] = bA.x; kacc[1] = bA.y; kacc[2] = bA.z; kacc[3] = bA.w;
      kacc[4] = bB.x; kacc[5] = bB.y; kacc[6] = bB.z; kacc[7] = bB.w;
    }
    const int gbase = (buf << 17) + (r << 6) + (fb << 1);
#pragma unroll
    for (int mm = 0; mm < 8; ++mm) {
      const unsigned long long* pp = partB + gbase + ((mm * 32 + g) << 9);
      U64H4 ua, ub;
      ua.u = __hip_atomic_load(pp, __ATOMIC_RELAXED, __HIP_MEMORY_SCOPE_AGENT);
      ub.u = __hip_atomic_load(pp + 1, __ATOMIC_RELAXED, __HIP_MEMORY_SCOPE_AGENT);
#pragma unroll
      for (int j = 0; j < 4; ++j) {
        kacc[j] += (float)ua.h[j];
        kacc[4 + j] += (float)ub.h[j];
      }
    }
#pragma unroll
    for (int j = 0; j < 8; ++j) kout[j] = kacc[j];
  };

  // ---- Butcher tableau ----------------------------------------------------
  const float AB[6][6] = {
      {(float)(1.0 / 5.0), 0, 0, 0, 0, 0},
      {(float)(3.0 / 40.0), (float)(9.0 / 40.0), 0, 0, 0, 0},
      {(float)(44.0 / 45.0), (float)(-56.0 / 15.0), (float)(32.0 / 9.0), 0, 0, 0},
      {(float)(19372.0 / 6561.0), (float)(-25360.0 / 2187.0),
       (float)(64448.0 / 6561.0), (float)(-212.0 / 729.0), 0, 0},
      {(float)(9017.0 / 3168.0), (float)(-355.0 / 33.0),
       (float)(46732.0 / 5247.0), (float)(49.0 / 176.0),
       (float)(-5103.0 / 18656.0), 0},
      {(float)(35.0 / 384.0), 0.0f, (float)(500.0 / 1113.0),
       (float)(125.0 / 192.0), (float)(-2187.0 / 6784.0), (float)(11.0 / 84.0)}};
  const float CC[7] = {0.0f, (float)(1.0 / 5.0), (float)(3.0 / 10.0),
                       (float)(4.0 / 5.0), (float)(8.0 / 9.0), 1.0f, 1.0f};
  const float DD[7] = {(float)(35.0 / 384.0 - 5179.0 / 57600.0), 0.0f,
                       (float)(500.0 / 1113.0 - 7571.0 / 16695.0),
                       (float)(125.0 / 192.0 - 393.0 / 640.0),
                       (float)(-2187.0 / 6784.0 + 92097.0 / 339200.0),
                       (float)(11.0 / 84.0 - 187.0 / 2100.0),
                       (float)(-1.0 / 40.0)};

  float t = 0.0f, dt = 0.05f;
  stage_eval(x, 0.0f, ks[0]);  // FSAL seed

  for (int it = 0; it < 64; ++it) {
    if (t >= 1.0f) break;  // controller is globally uniform -> exact
    const float dt_c = fmaxf(fminf(dt, 1.0f - t), 0.0f);

    float x5[8];
#pragma unroll
    for (int s = 1; s <= 6; ++s) {
      float xi[8];
#pragma unroll
      for (int j = 0; j < 8; ++j) {
        float v = x[j];
#pragma unroll
        for (int p = 0; p < 6; ++p)
          if (p < s) v = fmaf(dt_c * AB[s - 1][p], ks[p][j], v);
        xi[j] = v;
        if (s == 6) x5[j] = v;  // stage-7 point == x5 (FSAL)
      }
      stage_eval(xi, fmaf(CC[s], dt_c, t), ks[s]);
    }

    // member 0 of each group publishes its group's err sum to a slot
    if (m == 0) {
      float loc = 0.0f;
#pragma unroll
      for (int j = 0; j < 8; ++j) {
        float e = 0.0f;
#pragma unroll
        for (int s = 0; s < 7; ++s) e = fmaf(dt_c * DD[s], ks[s][j], e);
        const float scale = fmaf(1e-3f, fmaxf(fabsf(x[j]), fabsf(x5[j])), 1e-4f);
        const float rr = e / scale;
        loc = fmaf(rr, rr, loc);
      }
#pragma unroll
      for (int o = 32; o > 0; o >>= 1) loc += __shfl_down(loc, o);
      if (lane == 0) sred[w] = loc;
      __syncthreads();
      if (tid == 0) {
        const float s4 = sred[0] + sred[1] + sred[2] + sred[3];
        __hip_atomic_store(&errSlots[it * 32 + g], s4, __ATOMIC_RELAXED,
                           __HIP_MEMORY_SCOPE_AGENT);
      }
    }
    // wave 0 polls the 32 slots (sentinel: poison/init are negative)
    if (w == 0) {
      for (;;) {
        float v = 0.0f;
        bool okl = true;
        if (lane < 32) {
          v = __hip_atomic_load(&errSlots[it * 32 + lane], __ATOMIC_RELAXED,
                                __HIP_MEMORY_SCOPE_AGENT);
          okl = (v >= 0.0f);
        }
        if (__all(okl)) {
#pragma unroll
          for (int o = 32; o > 0; o >>= 1) v += __shfl_down(v, o);
          if (lane == 0) sbc[0] = v;
          break;
        }
      }
    }
    __syncthreads();
    const float total = sbc[0];
    const float err_norm = sqrtf(total * (1.0f / 65536.0f));
    const bool accept = err_norm <= 1.0f;
    float factor = 0.9f * powf(err_norm + 1e-10f, -0.2f);
    factor = fminf(fmaxf(factor, 0.2f), 5.0f);
    if (accept) {
      t = t + dt_c;
#pragma unroll
      for (int j = 0; j < 8; ++j) { x[j] = x5[j]; ks[0][j] = ks[6][j]; }
    }
    dt = dt_c * factor;
  }

  // ---- output: stack([x0, xf]) (member 0 only) ---------------------------
  if (m == 0) {
    float4* o0 = (float4*)(out + (8 * g + r) * 256 + fb * 8);
    const float4* xr = (const float4*)xrow;
    o0[0] = xr[0]; o0[1] = xr[1];
    float4 a0, a1;
    a0.x = x[0]; a0.y = x[1]; a0.z = x[2]; a0.w = x[3];
    a1.x = x[4]; a1.y = x[5]; a1.z = x[6]; a1.w = x[7];
    float4* o1 = (float4*)(out + 65536 + (8 * g + r) * 256 + fb * 8);
    o1[0] = a0; o1[1] = a1;
  }
}

extern "C" void kernel_launch(void* const* d_in, const int* in_sizes, int n_in,
                              void* d_out, int out_size, void* d_ws,
                              size_t ws_size, hipStream_t stream) {
  const float* x0 = (const float*)d_in[0];
  const float* W1 = (const float*)d_in[1];
  const float* b1 = (const float*)d_in[2];
  const float* W2 = (const float*)d_in[3];
  const float* b2 = (const float*)d_in[4];
  float* out = (float*)d_out;
  char* ws = (char*)d_ws;
  unsigned long long* partB = (unsigned long long*)ws;
  unsigned* stamps = (unsigned*)(ws + STAMP_OFF);
  float* errSlots = (float*)(ws + SLOT_OFF);

  hipFuncSetAttribute((const void*)neural_ode_dopri5,
                      hipFuncAttributeMaxDynamicSharedMemorySize, SMEM_BYTES);

  void* args[] = {&x0, &W1, &b1, &W2, &b2, &out, &partB, &stamps, &errSlots};
  hipLaunchCooperativeKernel((void*)neural_ode_dopri5, dim3(256), dim3(256),
                             args, SMEM_BYTES, stream);
}